// Round 7
// baseline (2252.720 us; speedup 1.0000x reference)
//
#include <hip/hip_runtime.h>
#include <math.h>

// KimiK2 MoE gate. Round 7 PROBE: tie-break toward HIGHER index in both
// group top-4 and expert top-8 (numpy reversed-argsort idiom), on round-4
// numerics (seq f32 FMA GEMM, CR-exp sigmoid, top2-sum groups, pairwise
// n=8 denom). Output: [T*8 indices as float][T*8 weights].

#define TT 16384
#define HH 7168
#define EE 256
#define BM 64
#define BK 32
#define NTH 256

struct SMem {
    union {
        struct { float xs[BK][BM]; float wl[BK][EE]; } st; // 8KB + 32KB
        float logits[32][EE];                              // 32KB (2 passes)
    } u;
    float bias[EE];
};

__global__ __launch_bounds__(NTH)
void moe_gate(const float* __restrict__ x, const float* __restrict__ w,
              const float* __restrict__ bias, float* __restrict__ out) {
    __shared__ SMem sm;
    const int tid = threadIdx.x;
    const int bm = blockIdx.x * BM;
    sm.bias[tid] = bias[tid]; // EE == NTH

    const int tc = tid & 31;  // expert col group: experts tc*8..tc*8+7
    const int tr = tid >> 5;  // token row group: tokens tr*8..tr*8+7

    float acc[8][8];
    #pragma unroll
    for (int i = 0; i < 8; ++i)
        #pragma unroll
        for (int j = 0; j < 8; ++j) acc[i][j] = 0.f;

    const float* xb = x + (size_t)bm * HH;

    for (int k0 = 0; k0 < HH; k0 += BK) {
        __syncthreads();
        #pragma unroll
        for (int p = 0; p < 2; ++p) {
            int q = tid + p * NTH;
            int tok = q >> 3, kq = q & 7;
            float4 v = *(const float4*)(xb + (size_t)tok * HH + k0 + kq * 4);
            sm.u.st.xs[kq * 4 + 0][tok] = v.x;
            sm.u.st.xs[kq * 4 + 1][tok] = v.y;
            sm.u.st.xs[kq * 4 + 2][tok] = v.z;
            sm.u.st.xs[kq * 4 + 3][tok] = v.w;
        }
        #pragma unroll
        for (int p = 0; p < 8; ++p) {
            int q = tid + p * NTH;
            int ex = q >> 3, kq = q & 7;
            float4 v = *(const float4*)(w + (size_t)ex * HH + k0 + kq * 4);
            sm.u.st.wl[kq * 4 + 0][ex] = v.x;
            sm.u.st.wl[kq * 4 + 1][ex] = v.y;
            sm.u.st.wl[kq * 4 + 2][ex] = v.z;
            sm.u.st.wl[kq * 4 + 3][ex] = v.w;
        }
        __syncthreads();
        // strict ascending-k FMA accumulation (BLAS microkernel chain)
        #pragma unroll 8
        for (int kk = 0; kk < BK; ++kk) {
            float4 xa = *(const float4*)&sm.u.st.xs[kk][tr * 8];
            float4 xc = *(const float4*)&sm.u.st.xs[kk][tr * 8 + 4];
            float4 wa = *(const float4*)&sm.u.st.wl[kk][tc * 8];
            float4 wc = *(const float4*)&sm.u.st.wl[kk][tc * 8 + 4];
            float xv[8] = {xa.x, xa.y, xa.z, xa.w, xc.x, xc.y, xc.z, xc.w};
            float wv[8] = {wa.x, wa.y, wa.z, wa.w, wc.x, wc.y, wc.z, wc.w};
            #pragma unroll
            for (int i = 0; i < 8; ++i)
                #pragma unroll
                for (int j = 0; j < 8; ++j)
                    acc[i][j] = fmaf(xv[i], wv[j], acc[i][j]);
        }
    }

    const int wave = tid >> 6, lane = tid & 63;

    for (int h = 0; h < 2; ++h) {
        __syncthreads();
        if ((tr >> 2) == h) {
            #pragma unroll
            for (int i = 0; i < 8; ++i)
                #pragma unroll
                for (int j = 0; j < 8; ++j)
                    sm.u.logits[(tr & 3) * 8 + i][tc * 8 + j] = acc[i][j];
        }
        __syncthreads();
        for (int tt = wave; tt < 32; tt += 4) {
            const int gt = bm + h * 32 + tt;
            float4 lg = *(const float4*)&sm.u.logits[tt][lane * 4];
            float lgv[4] = {lg.x, lg.y, lg.z, lg.w};
            float s[4], sc[4], m[4];
            #pragma unroll
            for (int j = 0; j < 4; ++j) {
                float e = (float)exp(-(double)lgv[j]);
                float u = __fadd_rn(1.0f, e);
                s[j] = __fdiv_rn(1.0f, u);
                sc[j] = __fadd_rn(s[j], sm.bias[lane * 4 + j]);
            }
            // group score = top2-sum of sc within group (round-4 form)
            float a1 = fmaxf(sc[0], sc[1]), a2 = fminf(sc[0], sc[1]);
            if (sc[2] > a1) { a2 = a1; a1 = sc[2]; } else a2 = fmaxf(a2, sc[2]);
            if (sc[3] > a1) { a2 = a1; a1 = sc[3]; } else a2 = fmaxf(a2, sc[3]);
            #pragma unroll
            for (int off = 1; off <= 4; off <<= 1) {
                float b1 = __shfl_xor(a1, off);
                float b2 = __shfl_xor(a2, off);
                float m1 = fmaxf(a1, b1);
                float m2 = fmaxf(fminf(a1, b1), (a1 >= b1) ? a2 : b2);
                a1 = m1; a2 = m2;
            }
            float gsc = __fadd_rn(a1, a2);
            float gsv[8];
            #pragma unroll
            for (int g = 0; g < 8; ++g) gsv[g] = __shfl(gsc, g * 8);
            int gm = lane >> 3;
            // ---- PROBE: ties -> HIGHER group index selected ----
            int rank = 0;
            #pragma unroll
            for (int hh = 0; hh < 8; ++hh)
                rank += (gsv[hh] > gsv[gm]) || (gsv[hh] == gsv[gm] && hh > gm);
            bool selg = rank < 4;
            #pragma unroll
            for (int j = 0; j < 4; ++j) m[j] = selg ? sc[j] : 0.0f;

            // iterative top-8 wave argmax; ---- PROBE: ties -> HIGHER index
            float selw = 0.f; int seli = 0;
            #pragma unroll
            for (int k = 0; k < 8; ++k) {
                float bv = m[0]; int bj = 0;
                #pragma unroll
                for (int j = 1; j < 4; ++j)
                    if (m[j] >= bv) { bv = m[j]; bj = j; } // higher j wins tie
                float v = bv; int ii = lane * 4 + bj;
                #pragma unroll
                for (int off = 1; off < 64; off <<= 1) {
                    float ov = __shfl_xor(v, off);
                    int oi = __shfl_xor(ii, off);
                    if (ov > v || (ov == v && oi > ii)) { v = ov; ii = oi; }
                }
                int oj = ii & 3, ol = ii >> 2;
                float cand = (oj == 0) ? s[0] : (oj == 1) ? s[1]
                           : (oj == 2) ? s[2] : s[3];
                float wgt = __shfl(cand, ol);
                if (lane == k) { seli = ii; selw = wgt; }
                if (lane == ol) {
                    if (oj == 0) m[0] = -1e30f;
                    else if (oj == 1) m[1] = -1e30f;
                    else if (oj == 2) m[2] = -1e30f;
                    else m[3] = -1e30f;
                }
            }
            // numpy n=8 pairwise-tree denom
            float wk[8];
            #pragma unroll
            for (int k = 0; k < 8; ++k) wk[k] = __shfl(selw, k);
            float denom = __fadd_rn(
                __fadd_rn(__fadd_rn(wk[0], wk[1]), __fadd_rn(wk[2], wk[3])),
                __fadd_rn(__fadd_rn(wk[4], wk[5]), __fadd_rn(wk[6], wk[7])));
            denom = __fadd_rn(denom, 1e-20f);
            if (lane < 8) {
                out[(size_t)gt * 8 + lane] = (float)seli;
                out[(size_t)TT * 8 + (size_t)gt * 8 + lane] =
                    __fmul_rn(__fdiv_rn(selw, denom), 2.5f);
            }
        }
    }
}

extern "C" void kernel_launch(void* const* d_in, const int* in_sizes, int n_in,
                              void* d_out, int out_size, void* d_ws, size_t ws_size,
                              hipStream_t stream) {
    const float* x    = (const float*)d_in[0];
    const float* w    = (const float*)d_in[1];
    const float* bias = (const float*)d_in[2];
    float* out = (float*)d_out;
    const int T = in_sizes[0] / HH; // 16384
    moe_gate<<<T / BM, NTH, 0, stream>>>(x, w, bias, out);
}

// Round 9
// 1663.816 us; speedup vs baseline: 1.3539x; 1.3539x over previous
//
#include <hip/hip_runtime.h>
#include <math.h>

// KimiK2 MoE gate. Round 9: round-8 architecture, plain C (no inline asm).
// Wave = 8 tokens x 256 experts. x loads via wave-uniform pointer (-> s_load),
// w staged in LDS [256][36] (pad 4) -> conflict-free ds_read_b128.
// GEMM chain + routing bit-identical to round 7 (ties -> higher index).
// Output: [T*8 indices as float][T*8 weights].

#define HH 7168
#define EE 256
#define BMT 32
#define BK 32
#define NTH 256
#define WPAD 36

typedef float v4f __attribute__((ext_vector_type(4)));

struct SMem {
    union {
        float wl[EE][WPAD];     // 36 KB padded w slice
        float logits[BMT][EE];  // 32 KB
    } u;
    float bias[EE];
};

__global__ __launch_bounds__(NTH, 2)
void moe_gate(const float* __restrict__ x, const float* __restrict__ w,
              const float* __restrict__ bias, float* __restrict__ out, int T) {
    __shared__ SMem sm;
    const int tid = threadIdx.x;
    const int bm = blockIdx.x * BMT;
    sm.bias[tid] = bias[tid];
    const int lane = tid & 63;
    const int wv = __builtin_amdgcn_readfirstlane(threadIdx.x >> 6);

    // w staging: thread (kg, eg0) stages rows eg0+32p, cols kg*4..kg*4+3
    const int kg = tid & 7;
    const int eg0 = tid >> 3;
    const float* wg = w + (size_t)eg0 * HH + kg * 4;

    // wave-uniform x row pointers (8 tokens per wave)
    const float* xr = x + (size_t)(bm + wv * 8) * HH;

    float acc[8][4];
    #pragma unroll
    for (int t = 0; t < 8; ++t)
        #pragma unroll
        for (int j = 0; j < 4; ++j) acc[t][j] = 0.f;

    // prologue: stage k0=0 w slice into registers
    v4f sreg[8];
    #pragma unroll
    for (int p = 0; p < 8; ++p)
        sreg[p] = *(const v4f*)(wg + (size_t)p * 32 * HH);

    for (int k0 = 0; k0 < HH; k0 += BK) {
        __syncthreads();
        #pragma unroll
        for (int p = 0; p < 8; ++p)
            *(v4f*)&sm.u.wl[eg0 + 32 * p][kg * 4] = sreg[p];
        __syncthreads();
        if (k0 + BK < HH) {
            const float* wgk = wg + k0 + BK;
            #pragma unroll
            for (int p = 0; p < 8; ++p)
                sreg[p] = *(const v4f*)(wgk + (size_t)p * 32 * HH);
        }
        #pragma unroll
        for (int q = 0; q < 8; ++q) {       // q: 4-k group within slice
            v4f w0 = *(const v4f*)&sm.u.wl[lane      ][q * 4];
            v4f w1 = *(const v4f*)&sm.u.wl[lane +  64][q * 4];
            v4f w2 = *(const v4f*)&sm.u.wl[lane + 128][q * 4];
            v4f w3 = *(const v4f*)&sm.u.wl[lane + 192][q * 4];
            v4f xv[8];
            #pragma unroll
            for (int t = 0; t < 8; ++t)
                xv[t] = *(const v4f*)(xr + (size_t)t * HH + k0 + q * 4);
            #pragma unroll
            for (int t = 0; t < 8; ++t) {
                #pragma unroll
                for (int c = 0; c < 4; ++c) {   // k ascends per (t,expert)
                    float xs = xv[t][c];
                    acc[t][0] = fmaf(xs, w0[c], acc[t][0]);
                    acc[t][1] = fmaf(xs, w1[c], acc[t][1]);
                    acc[t][2] = fmaf(xs, w2[c], acc[t][2]);
                    acc[t][3] = fmaf(xs, w3[c], acc[t][3]);
                }
            }
        }
    }

    __syncthreads();
    #pragma unroll
    for (int t = 0; t < 8; ++t)
        #pragma unroll
        for (int j = 0; j < 4; ++j)
            sm.u.logits[wv * 8 + t][lane + 64 * j] = acc[t][j];
    __syncthreads();

    // ---- routing: round-7 verbatim (ties -> higher index) ----
    for (int tt = wv; tt < BMT; tt += 4) {
        const int gt = bm + tt;
        float4 lg = *(const float4*)&sm.u.logits[tt][lane * 4];
        float lgv[4] = {lg.x, lg.y, lg.z, lg.w};
        float s[4], sc[4], m[4];
        #pragma unroll
        for (int j = 0; j < 4; ++j) {
            float e = (float)exp(-(double)lgv[j]);
            float u = __fadd_rn(1.0f, e);
            s[j] = __fdiv_rn(1.0f, u);
            sc[j] = __fadd_rn(s[j], sm.bias[lane * 4 + j]);
        }
        float a1 = fmaxf(sc[0], sc[1]), a2 = fminf(sc[0], sc[1]);
        if (sc[2] > a1) { a2 = a1; a1 = sc[2]; } else a2 = fmaxf(a2, sc[2]);
        if (sc[3] > a1) { a2 = a1; a1 = sc[3]; } else a2 = fmaxf(a2, sc[3]);
        #pragma unroll
        for (int off = 1; off <= 4; off <<= 1) {
            float b1 = __shfl_xor(a1, off);
            float b2 = __shfl_xor(a2, off);
            float m1 = fmaxf(a1, b1);
            float m2 = fmaxf(fminf(a1, b1), (a1 >= b1) ? a2 : b2);
            a1 = m1; a2 = m2;
        }
        float gsc = __fadd_rn(a1, a2);
        float gsv[8];
        #pragma unroll
        for (int g = 0; g < 8; ++g) gsv[g] = __shfl(gsc, g * 8);
        int gm = lane >> 3;
        int rank = 0;
        #pragma unroll
        for (int hh = 0; hh < 8; ++hh)
            rank += (gsv[hh] > gsv[gm]) || (gsv[hh] == gsv[gm] && hh > gm);
        bool selg = rank < 4;
        #pragma unroll
        for (int j = 0; j < 4; ++j) m[j] = selg ? sc[j] : 0.0f;

        float selw = 0.f; int seli = 0;
        #pragma unroll
        for (int k = 0; k < 8; ++k) {
            float bv = m[0]; int bj = 0;
            #pragma unroll
            for (int j = 1; j < 4; ++j)
                if (m[j] >= bv) { bv = m[j]; bj = j; }
            float v = bv; int ii = lane * 4 + bj;
            #pragma unroll
            for (int off = 1; off < 64; off <<= 1) {
                float ov = __shfl_xor(v, off);
                int oi = __shfl_xor(ii, off);
                if (ov > v || (ov == v && oi > ii)) { v = ov; ii = oi; }
            }
            int oj = ii & 3, ol = ii >> 2;
            float cand = (oj == 0) ? s[0] : (oj == 1) ? s[1]
                       : (oj == 2) ? s[2] : s[3];
            float wgt = __shfl(cand, ol);
            if (lane == k) { seli = ii; selw = wgt; }
            if (lane == ol) {
                if (oj == 0) m[0] = -1e30f;
                else if (oj == 1) m[1] = -1e30f;
                else if (oj == 2) m[2] = -1e30f;
                else m[3] = -1e30f;
            }
        }
        float wk[8];
        #pragma unroll
        for (int k = 0; k < 8; ++k) wk[k] = __shfl(selw, k);
        float denom = __fadd_rn(
            __fadd_rn(__fadd_rn(wk[0], wk[1]), __fadd_rn(wk[2], wk[3])),
            __fadd_rn(__fadd_rn(wk[4], wk[5]), __fadd_rn(wk[6], wk[7])));
        denom = __fadd_rn(denom, 1e-20f);
        if (lane < 8) {
            out[(size_t)gt * 8 + lane] = (float)seli;
            out[(size_t)T * 8 + (size_t)gt * 8 + lane] =
                __fmul_rn(__fdiv_rn(selw, denom), 2.5f);
        }
    }
}

extern "C" void kernel_launch(void* const* d_in, const int* in_sizes, int n_in,
                              void* d_out, int out_size, void* d_ws, size_t ws_size,
                              hipStream_t stream) {
    const float* x    = (const float*)d_in[0];
    const float* w    = (const float*)d_in[1];
    const float* bias = (const float*)d_in[2];
    float* out = (float*)d_out;
    const int T = in_sizes[0] / HH; // 16384
    moe_gate<<<T / BMT, NTH, 0, stream>>>(x, w, bias, out, T);
}